// Round 3
// baseline (775.394 us; speedup 1.0000x reference)
//
#include <hip/hip_runtime.h>
#include <math.h>

#define SEQ   2048
#define BATCH 2
#define NHEAD 8
#define HID   512
#define LG8   0.180336880f   /* log2(e)/8 */
#define MASKV -3.0e8f

typedef unsigned char  u8;
typedef unsigned short u16;
typedef short short8 __attribute__((ext_vector_type(8)));
typedef float f32x4  __attribute__((ext_vector_type(4)));

__device__ __forceinline__ u16 f2bf(float f) {
    unsigned u = __float_as_uint(f);
    u = (u + 0x7FFF + ((u >> 16) & 1)) >> 16;   // RNE
    return (u16)u;
}
__device__ __forceinline__ float bf2f(u16 h) {
    return __uint_as_float(((unsigned)h) << 16);
}
__device__ __forceinline__ void split2(float s, u16& h, u16& l) {
    h = f2bf(s); l = f2bf(s - bf2f(h));
}

// ---------- split activations (query,key_,value) into bf16 hi/lo ----------
__global__ __launch_bounds__(256) void conv_act(
    const float* __restrict__ q, const float* __restrict__ k, const float* __restrict__ v,
    u16* __restrict__ Qh, u16* __restrict__ Ql, u16* __restrict__ Kh, u16* __restrict__ Kl,
    u16* __restrict__ Vh, u16* __restrict__ Vl)
{
    const size_t i = ((size_t)blockIdx.x * 256 + threadIdx.x) * 4;
    float4 qv = *(const float4*)&q[i];
    float4 kv = *(const float4*)&k[i];
    float4 vv = *(const float4*)&v[i];
    ushort4 a, b, c, d, e, f;
    split2(qv.x, a.x, b.x); split2(qv.y, a.y, b.y); split2(qv.z, a.z, b.z); split2(qv.w, a.w, b.w);
    split2(kv.x, c.x, d.x); split2(kv.y, c.y, d.y); split2(kv.z, c.z, d.z); split2(kv.w, c.w, d.w);
    split2(vv.x, e.x, f.x); split2(vv.y, e.y, f.y); split2(vv.z, e.z, f.z); split2(vv.w, e.w, f.w);
    *(ushort4*)&Qh[i] = a; *(ushort4*)&Ql[i] = b;
    *(ushort4*)&Kh[i] = c; *(ushort4*)&Kl[i] = d;
    *(ushort4*)&Vh[i] = e; *(ushort4*)&Vl[i] = f;
}

// ---------- transpose + split the four 512x512 weight matrices ----------
// wt layout: [z][2][512 n][512 k] u16  (z: 0=Wq 1=Wk 2=Wv 3=Wo; 0=hi 1=lo)
__global__ __launch_bounds__(256) void conv_w(
    const float* __restrict__ W0, const float* __restrict__ W1,
    const float* __restrict__ W2, const float* __restrict__ W3,
    u16* __restrict__ wt)
{
    __shared__ float T[64][68];
    const float* Wz = (blockIdx.z == 0) ? W0 : (blockIdx.z == 1) ? W1 : (blockIdx.z == 2) ? W2 : W3;
    u16* wh = wt + (size_t)blockIdx.z * 2 * 262144;
    u16* wl = wh + 262144;
    const int t = threadIdx.x;
    const int k0 = blockIdx.x << 6, n0 = blockIdx.y << 6;
    {
        const int r = t >> 2, c = (t & 3) << 4;
        #pragma unroll
        for (int cc = 0; cc < 16; cc += 4)
            *(float4*)&T[r][c + cc] = *(const float4*)&Wz[(size_t)(k0 + r) * HID + n0 + c + cc];
    }
    __syncthreads();
    {
        const int n = t >> 2, kc = (t & 3) << 4;
        short8 h0, l0, h1, l1;
        #pragma unroll
        for (int e = 0; e < 8; ++e) {
            u16 hh, ll;
            split2(T[kc + e][n], hh, ll);     h0[e] = (short)hh; l0[e] = (short)ll;
            split2(T[kc + 8 + e][n], hh, ll); h1[e] = (short)hh; l1[e] = (short)ll;
        }
        const size_t o = (size_t)(n0 + n) * HID + k0 + kc;
        *(short8*)&wh[o] = h0; *(short8*)&wh[o + 8] = h1;
        *(short8*)&wl[o] = l0; *(short8*)&wl[o + 8] = l1;
    }
}

// ---------- fused pos/mask byte table ----------
__global__ __launch_bounds__(256) void conv_pm(
    const int* __restrict__ pos, const u8* __restrict__ mask, u8* __restrict__ pm)
{
    const size_t s = ((size_t)blockIdx.x * 256 + threadIdx.x) * 4;
    int4  p = *(const int4*)&pos[s & (size_t)(SEQ * SEQ - 1)];
    uchar4 m = *(const uchar4*)&mask[s];
    uchar4 o;
    o.x = m.x ? (u8)3 : (u8)p.x;
    o.y = m.y ? (u8)3 : (u8)p.y;
    o.z = m.z ? (u8)3 : (u8)p.z;
    o.w = m.w ? (u8)3 : (u8)p.w;
    *(uchar4*)&pm[s] = o;
}

// ---------- LDS-free bf16x3 GEMM: C[4096,512] = A @ W + bias ----------
// OMODE: 0 = fp32 out, 1 = u16 hi/lo out, 2 = u16 single out
template<int OMODE>
__global__ __launch_bounds__(256) void gemm_mfma(
    const u16* __restrict__ Ah, const u16* __restrict__ Al,
    const u16* __restrict__ Wh, const u16* __restrict__ Wl,
    const float* __restrict__ bias,
    float* __restrict__ Cf, u16* __restrict__ Ch, u16* __restrict__ Cl)
{
    const int tid = threadIdx.x;
    const int wave = tid >> 6, lane = tid & 63;
    const int quad = lane >> 4, l15 = lane & 15;
    const int row0 = blockIdx.x << 6, n0 = blockIdx.y << 6;
    const size_t abase = (size_t)(row0 + (wave << 4) + l15) * HID + (quad << 3);

    f32x4 acc[4] = {{0.f,0.f,0.f,0.f},{0.f,0.f,0.f,0.f},{0.f,0.f,0.f,0.f},{0.f,0.f,0.f,0.f}};
    #pragma unroll 4
    for (int k0 = 0; k0 < HID; k0 += 32) {
        const short8 ah = *(const short8*)&Ah[abase + k0];
        const short8 al = *(const short8*)&Al[abase + k0];
        #pragma unroll
        for (int nt = 0; nt < 4; ++nt) {
            const size_t wb = (size_t)(n0 + (nt << 4) + l15) * HID + k0 + (quad << 3);
            const short8 bh = *(const short8*)&Wh[wb];
            const short8 bl = *(const short8*)&Wl[wb];
            acc[nt] = __builtin_amdgcn_mfma_f32_16x16x32_bf16(ah, bh, acc[nt], 0, 0, 0);
            acc[nt] = __builtin_amdgcn_mfma_f32_16x16x32_bf16(al, bh, acc[nt], 0, 0, 0);
            acc[nt] = __builtin_amdgcn_mfma_f32_16x16x32_bf16(ah, bl, acc[nt], 0, 0, 0);
        }
    }
    #pragma unroll
    for (int nt = 0; nt < 4; ++nt) {
        const int col = n0 + (nt << 4) + l15;
        const float bv = bias[col];
        #pragma unroll
        for (int r = 0; r < 4; ++r) {
            const size_t idx = (size_t)(row0 + (wave << 4) + (quad << 2) + r) * HID + col;
            const float v = acc[nt][r] + bv;
            if (OMODE == 0) {
                Cf[idx] = v;
            } else if (OMODE == 1) {
                u16 hh, ll; split2(v, hh, ll);
                Ch[idx] = hh; Cl[idx] = ll;
            } else {
                Ch[idx] = f2bf(v);
            }
        }
    }
}

// ---------- transpose projected v: vb[b*S+j][h*64+d] -> vt[bh][d][j] ----------
__global__ __launch_bounds__(256) void transpose_v(
    const u16* __restrict__ vb, u16* __restrict__ vt)
{
    __shared__ u16 T[64][72];
    const int t = threadIdx.x;
    const int j0 = blockIdx.x << 6, bhh = blockIdx.y;
    const int b = bhh >> 3, h = bhh & 7;
    {
        const int r = t >> 2, c = (t & 3) << 4;
        const size_t g = (size_t)(b * SEQ + j0 + r) * HID + h * 64 + c;
        *(short8*)&T[r][c]     = *(const short8*)&vb[g];
        *(short8*)&T[r][c + 8] = *(const short8*)&vb[g + 8];
    }
    __syncthreads();
    {
        const int d = t >> 2, jc = (t & 3) << 4;
        short8 o0, o1;
        #pragma unroll
        for (int e = 0; e < 8; ++e) {
            o0[e] = (short)T[jc + e][d];
            o1[e] = (short)T[jc + 8 + e][d];
        }
        const size_t o = ((size_t)bhh * 64 + d) * SEQ + j0 + jc;
        *(short8*)&vt[o] = o0; *(short8*)&vt[o + 8] = o1;
    }
}

// ---------- rel dots: dqk[bh,i,r] = LG8 * sum_d (q+k)[b,i,h,d] * rel_table[r,d] ----------
__global__ __launch_bounds__(256) void rel_dots_kernel(
    const u16* __restrict__ qh, const u16* __restrict__ ql,
    const u16* __restrict__ kh, const u16* __restrict__ kl,
    const float* __restrict__ rel_table, float* __restrict__ dqk)
{
    const int w = blockIdx.x * 4 + (threadIdx.x >> 6);
    const int lane = threadIdx.x & 63;
    const int h = w % NHEAD;
    const int is = w / NHEAD;
    const int b = is / SEQ;
    const int i = is % SEQ;
    const size_t base = (size_t)is * HID + h * 64 + lane;
    const float s = (bf2f(qh[base]) + bf2f(ql[base])) + (bf2f(kh[base]) + bf2f(kl[base]));
    float p0 = s * rel_table[lane];
    float p1 = s * rel_table[64 + lane];
    float p2 = s * rel_table[128 + lane];
    #pragma unroll
    for (int off = 32; off; off >>= 1) {
        p0 += __shfl_xor(p0, off);
        p1 += __shfl_xor(p1, off);
        p2 += __shfl_xor(p2, off);
    }
    if (lane == 0) {
        size_t o = (((size_t)b * NHEAD + h) * SEQ + i) << 2;
        dqk[o + 0] = p0 * LG8; dqk[o + 1] = p1 * LG8; dqk[o + 2] = p2 * LG8;
    }
}

// ---------- pass A: P~ = exp2(qk*LG8 + dqk[pm]) bf16 scratch + row sums ----------
__global__ __launch_bounds__(256) void attn_exp(
    const u16* __restrict__ qh, const u16* __restrict__ ql,
    const u16* __restrict__ kh, const u16* __restrict__ kl,
    const float* __restrict__ dqk, const u8* __restrict__ pm,
    u16* __restrict__ Pt, float* __restrict__ invl)
{
    __shared__ float Ds[64][4];
    __shared__ __align__(16) u16 Pst[4][16 * 72];
    const int tid = threadIdx.x;
    const int wave = tid >> 6, lane = tid & 63;
    const int quad = lane >> 4, l15 = lane & 15;
    const int b = blockIdx.z, h = blockIdx.y, i0 = blockIdx.x << 6;
    const size_t bh = (size_t)(b * NHEAD + h);

    {
        const int i = tid >> 2, r = tid & 3;
        Ds[i][r] = (r == 3) ? MASKV : dqk[((bh * SEQ + i0 + i) << 2) + r];
    }
    __syncthreads();

    const size_t qbase = ((size_t)(b * SEQ + i0 + (wave << 4) + l15)) * HID + h * 64 + (quad << 3);
    const short8 aqh0 = *(const short8*)&qh[qbase];
    const short8 aqh1 = *(const short8*)&qh[qbase + 32];
    const short8 aql0 = *(const short8*)&ql[qbase];
    const short8 aql1 = *(const short8*)&ql[qbase + 32];

    const size_t prow = ((size_t)bh * SEQ + i0 + (wave << 4)) * SEQ;
    float srow[4] = {0.f, 0.f, 0.f, 0.f};

    for (int jt = 0; jt < SEQ / 64; ++jt) {
        const int j0 = jt << 6;
        #pragma unroll
        for (int sub = 0; sub < 4; ++sub) {
            const size_t kb = ((size_t)(b * SEQ + j0 + (sub << 4) + l15)) * HID + h * 64 + (quad << 3);
            const short8 bh0 = *(const short8*)&kh[kb];
            const short8 bh1 = *(const short8*)&kh[kb + 32];
            const short8 bl0 = *(const short8*)&kl[kb];
            const short8 bl1 = *(const short8*)&kl[kb + 32];
            f32x4 acc = {0.f, 0.f, 0.f, 0.f};
            acc = __builtin_amdgcn_mfma_f32_16x16x32_bf16(aqh0, bh0, acc, 0, 0, 0);
            acc = __builtin_amdgcn_mfma_f32_16x16x32_bf16(aqh1, bh1, acc, 0, 0, 0);
            acc = __builtin_amdgcn_mfma_f32_16x16x32_bf16(aql0, bh0, acc, 0, 0, 0);
            acc = __builtin_amdgcn_mfma_f32_16x16x32_bf16(aql1, bh1, acc, 0, 0, 0);
            acc = __builtin_amdgcn_mfma_f32_16x16x32_bf16(aqh0, bl0, acc, 0, 0, 0);
            acc = __builtin_amdgcn_mfma_f32_16x16x32_bf16(aqh1, bl1, acc, 0, 0, 0);
            #pragma unroll
            for (int r = 0; r < 4; ++r) {
                const int il = (wave << 4) + (quad << 2) + r;
                const u8 p = pm[(size_t)b * SEQ * SEQ + (size_t)(i0 + il) * SEQ + j0 + (sub << 4) + l15];
                const float e = exp2f(fmaf(acc[r], LG8, Ds[il][p]));
                srow[r] += e;
                Pst[wave][((quad << 2) + r) * 72 + (sub << 4) + l15] = f2bf(e);
            }
        }
        // wave-private vectorized store of this 16x64 tile
        const short8 p0 = *(const short8*)&Pst[wave][l15 * 72 + (quad << 4)];
        const short8 p1 = *(const short8*)&Pst[wave][l15 * 72 + (quad << 4) + 8];
        *(short8*)&Pt[prow + (size_t)l15 * SEQ + j0 + (quad << 4)]     = p0;
        *(short8*)&Pt[prow + (size_t)l15 * SEQ + j0 + (quad << 4) + 8] = p1;
    }
    #pragma unroll
    for (int r = 0; r < 4; ++r) {
        float s = srow[r];
        s += __shfl_xor(s, 1); s += __shfl_xor(s, 2);
        s += __shfl_xor(s, 4); s += __shfl_xor(s, 8);
        if (l15 == 0)
            invl[bh * SEQ + i0 + (wave << 4) + (quad << 2) + r] = 1.0f / s;
    }
}

// ---------- pass B: attn = P~ * invl (fp32, written once) + PV -> x (hi/lo) ----------
__global__ __launch_bounds__(256) void attn_pv2(
    const u16* __restrict__ Pt, const u16* __restrict__ vt,
    const float* __restrict__ invl,
    float* __restrict__ attn, u16* __restrict__ xh, u16* __restrict__ xl)
{
    __shared__ __align__(16) u16 Ps[4][16 * 72];
    const int tid = threadIdx.x;
    const int wave = tid >> 6, lane = tid & 63;
    const int quad = lane >> 4, l15 = lane & 15;
    const int b = blockIdx.z, h = blockIdx.y, i0 = blockIdx.x << 6;
    const size_t bh = (size_t)(b * NHEAD + h);

    const int rloc = lane >> 2;          // row 0..15 within the wave's tile
    const int cloc = (lane & 3) << 4;    // col chunk 0/16/32/48
    const int grow = i0 + (wave << 4) + rloc;
    const float inv = invl[bh * SEQ + grow];
    const size_t prow = ((size_t)bh * SEQ + grow) * SEQ;

    f32x4 accX[4] = {{0.f,0.f,0.f,0.f},{0.f,0.f,0.f,0.f},{0.f,0.f,0.f,0.f},{0.f,0.f,0.f,0.f}};

    for (int jt = 0; jt < SEQ / 64; ++jt) {
        const int j0 = jt << 6;
        const short8 t0 = *(const short8*)&Pt[prow + j0 + cloc];
        const short8 t1 = *(const short8*)&Pt[prow + j0 + cloc + 8];
        // normalized fp32 attn write (only write of the 268MB output)
        float4 o0 = { bf2f((u16)t0[0]) * inv, bf2f((u16)t0[1]) * inv, bf2f((u16)t0[2]) * inv, bf2f((u16)t0[3]) * inv };
        float4 o1 = { bf2f((u16)t0[4]) * inv, bf2f((u16)t0[5]) * inv, bf2f((u16)t0[6]) * inv, bf2f((u16)t0[7]) * inv };
        float4 o2 = { bf2f((u16)t1[0]) * inv, bf2f((u16)t1[1]) * inv, bf2f((u16)t1[2]) * inv, bf2f((u16)t1[3]) * inv };
        float4 o3 = { bf2f((u16)t1[4]) * inv, bf2f((u16)t1[5]) * inv, bf2f((u16)t1[6]) * inv, bf2f((u16)t1[7]) * inv };
        *(float4*)&attn[prow + j0 + cloc + 0]  = o0;
        *(float4*)&attn[prow + j0 + cloc + 4]  = o1;
        *(float4*)&attn[prow + j0 + cloc + 8]  = o2;
        *(float4*)&attn[prow + j0 + cloc + 12] = o3;
        // wave-private LDS stage for the A-operand
        *(short8*)&Ps[wave][rloc * 72 + cloc]     = t0;
        *(short8*)&Ps[wave][rloc * 72 + cloc + 8] = t1;
        #pragma unroll
        for (int kk = 0; kk < 2; ++kk) {
            const short8 ap = *(const short8*)&Ps[wave][l15 * 72 + (kk << 5) + (quad << 3)];
            #pragma unroll
            for (int nt = 0; nt < 4; ++nt) {
                const short8 bv = *(const short8*)&vt[((size_t)bh * 64 + (nt << 4) + l15) * SEQ + j0 + (kk << 5) + (quad << 3)];
                accX[nt] = __builtin_amdgcn_mfma_f32_16x16x32_bf16(ap, bv, accX[nt], 0, 0, 0);
            }
        }
    }
    float invr[4];
    #pragma unroll
    for (int r = 0; r < 4; ++r)
        invr[r] = invl[bh * SEQ + i0 + (wave << 4) + (quad << 2) + r];
    #pragma unroll
    for (int nt = 0; nt < 4; ++nt) {
        #pragma unroll
        for (int r = 0; r < 4; ++r) {
            const float v = accX[nt][r] * invr[r];
            const size_t idx = (size_t)(b * SEQ + i0 + (wave << 4) + (quad << 2) + r) * HID
                             + h * 64 + (nt << 4) + l15;
            u16 hh, ll; split2(v, hh, ll);
            xh[idx] = hh; xl[idx] = ll;
        }
    }
}

extern "C" void kernel_launch(void* const* d_in, const int* in_sizes, int n_in,
                              void* d_out, int out_size, void* d_ws, size_t ws_size,
                              hipStream_t stream) {
    (void)in_sizes; (void)n_in; (void)out_size; (void)ws_size;
    const float* query = (const float*)d_in[0];
    const float* key_  = (const float*)d_in[1];
    const float* value = (const float*)d_in[2];
    const u8*    mask  = (const u8*)d_in[3];
    const int*   pos   = (const int*)d_in[4];
    const float* Wq = (const float*)d_in[5];
    const float* bq = (const float*)d_in[6];
    const float* Wk = (const float*)d_in[7];
    const float* bk = (const float*)d_in[8];
    const float* Wv = (const float*)d_in[9];
    const float* bv = (const float*)d_in[10];
    const float* Wo = (const float*)d_in[11];
    const float* bo = (const float*)d_in[12];
    const float* rel_table = (const float*)d_in[13];

    float* out  = (float*)d_out;
    float* attn = out + (size_t)BATCH * SEQ * HID;

    const size_t NE = (size_t)BATCH * SEQ * HID;   // 2,097,152
    u16* w = (u16*)d_ws;
    u16* qh  = w; w += NE;   u16* ql  = w; w += NE;
    u16* kh  = w; w += NE;   u16* kl  = w; w += NE;
    u16* vb  = w; w += NE;
    u16* Qih = w; w += NE;   u16* Qil = w; w += NE;
    u16* Kih = w; w += NE;   u16* Kil = w; w += NE;
    u16* Vih = w; w += NE;   u16* Vil = w; w += NE;
    u16* xh  = w; w += NE;   u16* xl  = w; w += NE;
    u16* vt  = w; w += NE;
    u16* wt  = w; w += (size_t)4 * 2 * 262144;
    u16* Pt  = w; w += (size_t)BATCH * NHEAD * SEQ * SEQ;   // 67,108,864 u16
    float* dqk  = (float*)w;
    float* invl = dqk + (size_t)BATCH * NHEAD * SEQ * 4;
    u8*    pm   = (u8*)(invl + (size_t)BATCH * NHEAD * SEQ);

    const dim3 blk(256);
    const int M = BATCH * SEQ;   // 4096

    conv_act<<<dim3(2048), blk, 0, stream>>>(query, key_, value, Qih, Qil, Kih, Kil, Vih, Vil);
    conv_w<<<dim3(8, 8, 4), blk, 0, stream>>>(Wq, Wk, Wv, Wo, wt);
    conv_pm<<<dim3(8192), blk, 0, stream>>>(pos, mask, pm);

    u16* wtq = wt;            u16* wtk = wt + 2 * 262144;
    u16* wtv = wt + 4 * 262144; u16* wto = wt + 6 * 262144;
    gemm_mfma<1><<<dim3(M / 64, HID / 64), blk, 0, stream>>>(
        Qih, Qil, wtq, wtq + 262144, bq, nullptr, qh, ql);
    gemm_mfma<1><<<dim3(M / 64, HID / 64), blk, 0, stream>>>(
        Kih, Kil, wtk, wtk + 262144, bk, nullptr, kh, kl);
    gemm_mfma<2><<<dim3(M / 64, HID / 64), blk, 0, stream>>>(
        Vih, Vil, wtv, wtv + 262144, bv, nullptr, vb, nullptr);
    transpose_v<<<dim3(SEQ / 64, BATCH * NHEAD), blk, 0, stream>>>(vb, vt);
    rel_dots_kernel<<<dim3(M * NHEAD / 4), blk, 0, stream>>>(qh, ql, kh, kl, rel_table, dqk);

    attn_exp<<<dim3(SEQ / 64, NHEAD, BATCH), blk, 0, stream>>>(
        qh, ql, kh, kl, dqk, pm, Pt, invl);
    attn_pv2<<<dim3(SEQ / 64, NHEAD, BATCH), blk, 0, stream>>>(
        Pt, vt, invl, attn, xh, xl);

    gemm_mfma<0><<<dim3(M / 64, HID / 64), blk, 0, stream>>>(
        xh, xl, wto, wto + 262144, bo, out, nullptr, nullptr);
}